// Round 1
// baseline (1351.348 us; speedup 1.0000x reference)
//
#include <hip/hip_runtime.h>
#include <hip/hip_bf16.h>
#include <cstdint>

#define N_NODES 100000
#define N_EDGES 1600000
#define N_GRAPHS 512
#define N_LAYERS 3

// ---------------- edge dtype detection (int32 vs int64) ----------------
// If edge_index is int64 (values < 2^31), every odd 32-bit word is 0.
__global__ void k_detect64(const int* __restrict__ e, int* __restrict__ flag) {
  if (threadIdx.x == 0 && blockIdx.x == 0) {
    int any = 0;
    for (int i = 1; i < 128; i += 2) any |= e[i];
    *flag = (any == 0) ? 1 : 0;
  }
}

// ---------------- CSR build ----------------
__global__ __launch_bounds__(256) void k_degree(const int* __restrict__ e32,
    const long long* __restrict__ e64, const int* __restrict__ flag,
    int* __restrict__ deg) {
  int i = blockIdx.x * 256 + threadIdx.x;
  if (i >= N_EDGES) return;
  int d;
  if (*flag) d = (int)e64[N_EDGES + i];
  else       d = e32[N_EDGES + i];
  atomicAdd(&deg[d], 1);
}

__global__ __launch_bounds__(1024) void k_scan_block(const int* __restrict__ deg,
    int* __restrict__ rptr, int* __restrict__ bsum) {
  __shared__ int sd[1024];
  int t = threadIdx.x;
  int base = blockIdx.x * 4096 + t * 4;
  int4 v = make_int4(0, 0, 0, 0);
  if (base + 3 < N_NODES) {
    v = *(const int4*)&deg[base];
  } else {
    if (base + 0 < N_NODES) v.x = deg[base + 0];
    if (base + 1 < N_NODES) v.y = deg[base + 1];
    if (base + 2 < N_NODES) v.z = deg[base + 2];
  }
  int s = v.x + v.y + v.z + v.w;
  sd[t] = s;
  __syncthreads();
  for (int off = 1; off < 1024; off <<= 1) {
    int add = (t >= off) ? sd[t - off] : 0;
    __syncthreads();
    sd[t] += add;
    __syncthreads();
  }
  int excl = sd[t] - s;
  int vv[4] = {v.x, v.y, v.z, v.w};
  int run = excl;
  #pragma unroll
  for (int j = 0; j < 4; ++j) {
    if (base + j < N_NODES) rptr[base + j] = run;
    run += vv[j];
  }
  if (t == 1023) bsum[blockIdx.x] = sd[1023];
}

__global__ void k_scan_sums(int* __restrict__ bsum) {
  if (threadIdx.x == 0 && blockIdx.x == 0) {
    int run = 0;
    for (int i = 0; i < 25; ++i) { int x = bsum[i]; bsum[i] = run; run += x; }
  }
}

__global__ __launch_bounds__(1024) void k_scan_add(int* __restrict__ rptr,
    const int* __restrict__ bsum) {
  int i = blockIdx.x * 1024 + threadIdx.x;
  if (i == 0 && blockIdx.x == 0) rptr[N_NODES] = N_EDGES;
  if (i < N_NODES) rptr[i] += bsum[i >> 12];
}

__global__ __launch_bounds__(256) void k_fill(const int* __restrict__ e32,
    const long long* __restrict__ e64, const int* __restrict__ flag,
    const int* __restrict__ rptr, int* __restrict__ cursor, int* __restrict__ srcs) {
  int i = blockIdx.x * 256 + threadIdx.x;
  if (i >= N_EDGES) return;
  int s, d;
  if (*flag) { s = (int)e64[i]; d = (int)e64[N_EDGES + i]; }
  else       { s = e32[i];      d = e32[N_EDGES + i]; }
  int pos = atomicAdd(&cursor[d], 1);
  srcs[rptr[d] + pos] = s;
}

// ---------------- fp32 GEMM: out = act(A[N,128] @ W[128,128] + b) (+res) ----------------
// Block: 32 rows x 64 cols, 256 threads, 8 outputs/thread (2 rows x 4 cols).
// LDS: W^T chunk [64][132], A tile [32][132]; stride 132 keeps b128 reads ~conflict-free.
template <bool RELU, bool RES>
__global__ __launch_bounds__(256) void k_gemm128(const float* __restrict__ A,
    const float* __restrict__ W, const float* __restrict__ bias,
    const float* __restrict__ res, float* __restrict__ out) {
  __shared__ float sW[64][132];
  __shared__ float sA[32][132];
  const int t = threadIdx.x;
  const int row0 = (blockIdx.x >> 1) * 32;
  const int c0 = (blockIdx.x & 1) * 64;

  for (int idx = t; idx < 64 * 128; idx += 256) {
    int c = idx & 63, k = idx >> 6;
    sW[c][k] = W[k * 128 + c0 + c];
  }
  for (int idx = t; idx < 32 * 128; idx += 256) {
    int k = idx & 127, r = idx >> 7;
    sA[r][k] = A[(size_t)(row0 + r) * 128 + k];
  }
  __syncthreads();

  const int tx = t & 15, ty = t >> 4;
  float acc0[4] = {0.f, 0.f, 0.f, 0.f};
  float acc1[4] = {0.f, 0.f, 0.f, 0.f};
  #pragma unroll 8
  for (int k0 = 0; k0 < 128; k0 += 4) {
    float4 a0 = *(const float4*)&sA[ty][k0];
    float4 a1 = *(const float4*)&sA[ty + 16][k0];
    #pragma unroll
    for (int j = 0; j < 4; ++j) {
      float4 w = *(const float4*)&sW[tx + 16 * j][k0];
      acc0[j] += a0.x * w.x + a0.y * w.y + a0.z * w.z + a0.w * w.w;
      acc1[j] += a1.x * w.x + a1.y * w.y + a1.z * w.z + a1.w * w.w;
    }
  }
  #pragma unroll
  for (int j = 0; j < 4; ++j) {
    int c = c0 + tx + 16 * j;
    float b = bias[c];
    float v0 = acc0[j] + b;
    float v1 = acc1[j] + b;
    if (RELU) { v0 = fmaxf(v0, 0.f); v1 = fmaxf(v1, 0.f); }
    size_t o0 = (size_t)(row0 + ty) * 128 + c;
    size_t o1 = (size_t)(row0 + ty + 16) * 128 + c;
    if (RES) { v0 += res[o0]; v1 += res[o1]; }
    out[o0] = v0;
    out[o1] = v1;
  }
}

// ---------------- CSR aggregation: agg[v] = sum_{e: dst=v} msg[src[e]] ----------------
// One wave per node; lane holds 2 columns (float2 -> 512B coalesced row reads).
__global__ __launch_bounds__(256) void k_aggregate(const int* __restrict__ rptr,
    const int* __restrict__ srcs, const float* __restrict__ msg,
    float* __restrict__ agg) {
  int wid = blockIdx.x * 4 + (threadIdx.x >> 6);
  int lane = threadIdx.x & 63;
  if (wid >= N_NODES) return;
  int beg = rptr[wid], end = rptr[wid + 1];
  float ax = 0.f, ay = 0.f;
  int e = beg;
  for (; e + 2 <= end; e += 2) {
    int s0 = srcs[e], s1 = srcs[e + 1];
    float2 m0 = *(const float2*)&msg[(size_t)s0 * 128 + lane * 2];
    float2 m1 = *(const float2*)&msg[(size_t)s1 * 128 + lane * 2];
    ax += m0.x + m1.x;
    ay += m0.y + m1.y;
  }
  if (e < end) {
    int s = srcs[e];
    float2 m = *(const float2*)&msg[(size_t)s * 128 + lane * 2];
    ax += m.x;
    ay += m.y;
  }
  float2 r;
  r.x = ax;
  r.y = ay;
  *(float2*)&agg[(size_t)wid * 128 + lane * 2] = r;
}

// ---------------- pooling over sorted batch ids ----------------
__global__ __launch_bounds__(128) void k_pool(const float* __restrict__ h,
    const int* __restrict__ batch, float* __restrict__ g) {
  int t = threadIdx.x;  // column
  int v0 = blockIdx.x * 256;
  int v1 = min(v0 + 256, N_NODES);
  if (v0 >= N_NODES) return;
  int cur = batch[v0];
  float acc = 0.f;
  for (int v = v0; v < v1; ++v) {
    int b = batch[v];
    if (b != cur) {
      atomicAdd(&g[cur * 128 + t], acc);
      acc = 0.f;
      cur = b;
    }
    acc += h[(size_t)v * 128 + t];
  }
  atomicAdd(&g[cur * 128 + t], acc);
}

// ---------------- output heads ----------------
__global__ __launch_bounds__(128) void k_head(const float* __restrict__ g,
    const float* __restrict__ Wm, const float* __restrict__ bm,
    const float* __restrict__ Wl, const float* __restrict__ bl,
    float* __restrict__ out) {
  __shared__ float sg[128];
  int gr = blockIdx.x, t = threadIdx.x;
  sg[t] = g[gr * 128 + t];
  __syncthreads();
  const float* W = (t < 64) ? Wm : Wl;
  const float* b = (t < 64) ? bm : bl;
  int c = t & 63;
  float acc = b[c];
  #pragma unroll 8
  for (int k = 0; k < 128; ++k) acc += sg[k] * W[k * 64 + c];
  out[(size_t)(t < 64 ? 0 : N_GRAPHS * 64) + (size_t)gr * 64 + c] = acc;
}

// ---------------- host ----------------
extern "C" void kernel_launch(void* const* d_in, const int* in_sizes, int n_in,
                              void* d_out, int out_size, void* d_ws, size_t ws_size,
                              hipStream_t stream) {
  const float* x      = (const float*)d_in[0];
  const int* e32      = (const int*)d_in[1];
  const long long* e64 = (const long long*)d_in[1];
  const int* batch    = (const int*)d_in[2];
  const float* W_in   = (const float*)d_in[3];
  const float* b_in   = (const float*)d_in[4];
  const float* W_msg  = (const float*)d_in[5];
  const float* b_msg  = (const float*)d_in[6];
  const float* W_upd  = (const float*)d_in[7];
  const float* b_upd  = (const float*)d_in[8];
  const float* W_mean = (const float*)d_in[9];
  const float* b_mean = (const float*)d_in[10];
  const float* W_lv   = (const float*)d_in[11];
  const float* b_lv   = (const float*)d_in[12];
  float* out = (float*)d_out;

  char* p = (char*)d_ws;
  auto alloc = [&](size_t bytes) {
    char* r = p;
    p += (bytes + 255) & ~(size_t)255;
    return r;
  };
  float* bufA  = (float*)alloc((size_t)N_NODES * 128 * 4);
  float* bufB  = (float*)alloc((size_t)N_NODES * 128 * 4);
  float* bufC  = (float*)alloc((size_t)N_NODES * 128 * 4);
  int* srcs    = (int*)alloc((size_t)N_EDGES * 4);
  int* deg     = (int*)alloc((size_t)(N_NODES + 4) * 4);
  int* rptr    = (int*)alloc((size_t)(N_NODES + 4) * 4);
  int* cursor  = (int*)alloc((size_t)N_NODES * 4);
  int* bsum    = (int*)alloc(64 * 4);
  int* flag    = (int*)alloc(64 * 4);
  float* g     = (float*)alloc((size_t)N_GRAPHS * 128 * 4);

  hipMemsetAsync(deg, 0, (size_t)N_NODES * 4, stream);
  hipMemsetAsync(cursor, 0, (size_t)N_NODES * 4, stream);
  hipMemsetAsync(g, 0, (size_t)N_GRAPHS * 128 * 4, stream);

  // CSR build
  k_detect64<<<1, 64, 0, stream>>>(e32, flag);
  k_degree<<<(N_EDGES + 255) / 256, 256, 0, stream>>>(e32, e64, flag, deg);
  k_scan_block<<<25, 1024, 0, stream>>>(deg, rptr, bsum);
  k_scan_sums<<<1, 64, 0, stream>>>(bsum);
  k_scan_add<<<(N_NODES + 1023) / 1024, 1024, 0, stream>>>(rptr, bsum);
  k_fill<<<(N_EDGES + 255) / 256, 256, 0, stream>>>(e32, e64, flag, rptr, cursor, srcs);

  const int gemm_grid = (N_NODES / 32) * 2;

  // input layer
  k_gemm128<true, false><<<gemm_grid, 256, 0, stream>>>(x, W_in, b_in, nullptr, bufA);

  float* h = bufA;
  float* tmp = bufB;
  for (int l = 0; l < N_LAYERS; ++l) {
    const float* Wm = W_msg + (size_t)l * 128 * 128;
    const float* bm = b_msg + (size_t)l * 128;
    const float* Wu = W_upd + (size_t)l * 128 * 128;
    const float* bu = b_upd + (size_t)l * 128;
    // messages = relu(h @ Wm + bm)
    k_gemm128<true, false><<<gemm_grid, 256, 0, stream>>>(h, Wm, bm, nullptr, tmp);
    // agg = scatter-sum over CSR
    k_aggregate<<<N_NODES / 4, 256, 0, stream>>>(rptr, srcs, tmp, bufC);
    // h = relu(agg @ Wu + bu) + h   (write into tmp, then swap)
    k_gemm128<true, true><<<gemm_grid, 256, 0, stream>>>(bufC, Wu, bu, h, tmp);
    float* sw = h; h = tmp; tmp = sw;
  }

  // graph pooling + heads
  k_pool<<<(N_NODES + 255) / 256, 128, 0, stream>>>(h, batch, g);
  k_head<<<N_GRAPHS, 128, 0, stream>>>(g, W_mean, b_mean, W_lv, b_lv, out);
}

// Round 2
// 743.994 us; speedup vs baseline: 1.8163x; 1.8163x over previous
//
#include <hip/hip_runtime.h>
#include <hip/hip_bf16.h>
#include <cstdint>

#define N_NODES 100000
#define N_EDGES 1600000
#define N_GRAPHS 512
#define N_LAYERS 3

typedef __bf16 bf16x8 __attribute__((ext_vector_type(8)));
typedef float f32x4 __attribute__((ext_vector_type(4)));

__device__ __forceinline__ float bf2f(ushort u) {
  uint v = ((uint)u) << 16;
  return __builtin_bit_cast(float, v);
}
__device__ __forceinline__ ushort f2bf(float f) {
  uint u = __builtin_bit_cast(uint, f);
  u += 0x7FFF + ((u >> 16) & 1);   // RNE
  return (ushort)(u >> 16);
}

// ---------------- edge dtype detection (int32 vs int64) ----------------
__global__ void k_detect64(const int* __restrict__ e, int* __restrict__ flag) {
  if (threadIdx.x == 0 && blockIdx.x == 0) {
    int any = 0;
    for (int i = 1; i < 128; i += 2) any |= e[i];
    *flag = (any == 0) ? 1 : 0;
  }
}

// ---------------- CSR build ----------------
__global__ __launch_bounds__(256) void k_degree(const int* __restrict__ e32,
    const long long* __restrict__ e64, const int* __restrict__ flag,
    int* __restrict__ deg) {
  int i = blockIdx.x * 256 + threadIdx.x;
  if (i >= N_EDGES) return;
  int d;
  if (*flag) d = (int)e64[N_EDGES + i];
  else       d = e32[N_EDGES + i];
  atomicAdd(&deg[d], 1);
}

__global__ __launch_bounds__(1024) void k_scan_block(const int* __restrict__ deg,
    int* __restrict__ rptr, int* __restrict__ bsum) {
  __shared__ int sd[1024];
  int t = threadIdx.x;
  int base = blockIdx.x * 4096 + t * 4;
  int4 v = make_int4(0, 0, 0, 0);
  if (base + 3 < N_NODES) {
    v = *(const int4*)&deg[base];
  } else {
    if (base + 0 < N_NODES) v.x = deg[base + 0];
    if (base + 1 < N_NODES) v.y = deg[base + 1];
    if (base + 2 < N_NODES) v.z = deg[base + 2];
  }
  int s = v.x + v.y + v.z + v.w;
  sd[t] = s;
  __syncthreads();
  for (int off = 1; off < 1024; off <<= 1) {
    int add = (t >= off) ? sd[t - off] : 0;
    __syncthreads();
    sd[t] += add;
    __syncthreads();
  }
  int excl = sd[t] - s;
  int vv[4] = {v.x, v.y, v.z, v.w};
  int run = excl;
  #pragma unroll
  for (int j = 0; j < 4; ++j) {
    if (base + j < N_NODES) rptr[base + j] = run;
    run += vv[j];
  }
  if (t == 1023) bsum[blockIdx.x] = sd[1023];
}

__global__ void k_scan_sums(int* __restrict__ bsum) {
  if (threadIdx.x == 0 && blockIdx.x == 0) {
    int run = 0;
    for (int i = 0; i < 25; ++i) { int x = bsum[i]; bsum[i] = run; run += x; }
  }
}

__global__ __launch_bounds__(1024) void k_scan_add(int* __restrict__ rptr,
    const int* __restrict__ bsum) {
  int i = blockIdx.x * 1024 + threadIdx.x;
  if (i == 0 && blockIdx.x == 0) rptr[N_NODES] = N_EDGES;
  if (i < N_NODES) rptr[i] += bsum[i >> 12];
}

__global__ __launch_bounds__(256) void k_fill(const int* __restrict__ e32,
    const long long* __restrict__ e64, const int* __restrict__ flag,
    const int* __restrict__ rptr, int* __restrict__ cursor, int* __restrict__ srcs) {
  int i = blockIdx.x * 256 + threadIdx.x;
  if (i >= N_EDGES) return;
  int s, d;
  if (*flag) { s = (int)e64[i]; d = (int)e64[N_EDGES + i]; }
  else       { s = e32[i];      d = e32[N_EDGES + i]; }
  int pos = atomicAdd(&cursor[d], 1);
  srcs[rptr[d] + pos] = s;
}

// ---------------- prep: x fp32 -> bf16 ----------------
__global__ __launch_bounds__(256) void k_cvt_x(const float* __restrict__ x,
    ushort* __restrict__ xb) {
  size_t i = ((size_t)blockIdx.x * 256 + threadIdx.x) * 8;  // grid sized exactly
  float4 a = *(const float4*)&x[i];
  float4 b = *(const float4*)&x[i + 4];
  ushort4 lo, hi;
  lo.x = f2bf(a.x); lo.y = f2bf(a.y); lo.z = f2bf(a.z); lo.w = f2bf(a.w);
  hi.x = f2bf(b.x); hi.y = f2bf(b.y); hi.z = f2bf(b.z); hi.w = f2bf(b.w);
  *(ushort4*)&xb[i] = lo;
  *(ushort4*)&xb[i + 4] = hi;
}

// ---------------- prep: weights fp32 -> bf16 transposed Wt[c][k] ----------------
__global__ __launch_bounds__(256) void k_prep_w(const float* __restrict__ W_in,
    const float* __restrict__ W_msg, const float* __restrict__ W_upd,
    ushort* __restrict__ Wt) {
  int b = blockIdx.x;  // 0: in, 1..3: msg[l], 4..6: upd[l]
  const float* W = (b == 0) ? W_in : (b <= 3 ? W_msg + (size_t)(b - 1) * 16384
                                             : W_upd + (size_t)(b - 4) * 16384);
  ushort* O = Wt + (size_t)b * 16384;
  for (int i = threadIdx.x; i < 16384; i += 256) {
    int k = i >> 7, c = i & 127;
    O[c * 128 + k] = f2bf(W[i]);
  }
}

// ---------------- bf16 MFMA GEMM: out = relu(A @ W + b) (+res), all [*,128] ----------------
// block: 64 rows x 128 cols, 4 waves; wave w covers cols [32w, 32w+32)
template <bool RES>
__global__ __launch_bounds__(256) void k_gemm_bf16(const ushort* __restrict__ A,
    const ushort* __restrict__ Wt, const float* __restrict__ bias,
    const ushort* __restrict__ res, ushort* __restrict__ out) {
  __shared__ ushort sA[64][136];   // pad: 272B row stride -> <=2-way bank alias (free)
  __shared__ ushort sW[128][136];  // sW[col][k]
  const int t = threadIdx.x;
  const int row0 = blockIdx.x * 64;

  #pragma unroll
  for (int i = 0; i < 4; ++i) {            // A tile: 64 x 128 bf16
    int c = t + 256 * i;
    int r = c >> 4, k8 = (c & 15) * 8;
    int gr = min(row0 + r, N_NODES - 1);
    *(uint4*)&sA[r][k8] = *(const uint4*)&A[(size_t)gr * 128 + k8];
  }
  #pragma unroll
  for (int i = 0; i < 8; ++i) {            // W^T: 128 x 128 bf16
    int c = t + 256 * i;
    int r = c >> 4, k8 = (c & 15) * 8;
    *(uint4*)&sW[r][k8] = *(const uint4*)&Wt[r * 128 + k8];
  }
  __syncthreads();

  const int lane = t & 63;
  const int col0 = (t >> 6) * 32;
  const int lr = lane & 15, lk = (lane >> 4) * 8;

  f32x4 acc[4][2] = {};
  #pragma unroll
  for (int kk = 0; kk < 4; ++kk) {
    int kb = kk * 32 + lk;
    bf16x8 b0 = *(const bf16x8*)&sW[col0 + lr][kb];
    bf16x8 b1 = *(const bf16x8*)&sW[col0 + 16 + lr][kb];
    #pragma unroll
    for (int m = 0; m < 4; ++m) {
      bf16x8 a = *(const bf16x8*)&sA[m * 16 + lr][kb];
      acc[m][0] = __builtin_amdgcn_mfma_f32_16x16x32_bf16(a, b0, acc[m][0], 0, 0, 0);
      acc[m][1] = __builtin_amdgcn_mfma_f32_16x16x32_bf16(a, b1, acc[m][1], 0, 0, 0);
    }
  }

  const int rb = (lane >> 4) * 4;   // C/D: row=(lane>>4)*4+j, col=lane&15  [m89]
  #pragma unroll
  for (int n = 0; n < 2; ++n) {
    int col = col0 + n * 16 + lr;
    float bv = bias[col];
    #pragma unroll
    for (int m = 0; m < 4; ++m) {
      #pragma unroll
      for (int j = 0; j < 4; ++j) {
        int r = row0 + m * 16 + rb + j;
        if (r < N_NODES) {
          float v = fmaxf(acc[m][n][j] + bv, 0.f);
          if (RES) v += bf2f(res[(size_t)r * 128 + col]);
          out[(size_t)r * 128 + col] = f2bf(v);
        }
      }
    }
  }
}

// ---------------- CSR aggregation (bf16 msg): one wave per node ----------------
__global__ __launch_bounds__(256) void k_aggregate(const int* __restrict__ rptr,
    const int* __restrict__ srcs, const ushort* __restrict__ msg,
    ushort* __restrict__ agg) {
  int wid = blockIdx.x * 4 + (threadIdx.x >> 6);
  int lane = threadIdx.x & 63;
  int beg = rptr[wid], end = rptr[wid + 1];
  float ax = 0.f, ay = 0.f;
  int e = beg;
  for (; e + 2 <= end; e += 2) {
    int s0 = srcs[e], s1 = srcs[e + 1];
    uint m0 = *(const uint*)&msg[(size_t)s0 * 128 + lane * 2];
    uint m1 = *(const uint*)&msg[(size_t)s1 * 128 + lane * 2];
    ax += bf2f((ushort)m0) + bf2f((ushort)m1);
    ay += bf2f((ushort)(m0 >> 16)) + bf2f((ushort)(m1 >> 16));
  }
  if (e < end) {
    uint m = *(const uint*)&msg[(size_t)srcs[e] * 128 + lane * 2];
    ax += bf2f((ushort)m);
    ay += bf2f((ushort)(m >> 16));
  }
  uint r = (uint)f2bf(ax) | ((uint)f2bf(ay) << 16);
  *(uint*)&agg[(size_t)wid * 128 + lane * 2] = r;
}

// ---------------- pooling over sorted batch ids (bf16 h -> fp32 g) ----------------
__global__ __launch_bounds__(128) void k_pool(const ushort* __restrict__ h,
    const int* __restrict__ batch, float* __restrict__ g) {
  int t = threadIdx.x;  // column
  int v0 = blockIdx.x * 256;
  int v1 = min(v0 + 256, N_NODES);
  if (v0 >= N_NODES) return;
  int cur = batch[v0];
  float acc = 0.f;
  for (int v = v0; v < v1; ++v) {
    int b = batch[v];
    if (b != cur) {
      atomicAdd(&g[cur * 128 + t], acc);
      acc = 0.f;
      cur = b;
    }
    acc += bf2f(h[(size_t)v * 128 + t]);
  }
  atomicAdd(&g[cur * 128 + t], acc);
}

// ---------------- output heads (fp32) ----------------
__global__ __launch_bounds__(128) void k_head(const float* __restrict__ g,
    const float* __restrict__ Wm, const float* __restrict__ bm,
    const float* __restrict__ Wl, const float* __restrict__ bl,
    float* __restrict__ out) {
  __shared__ float sg[128];
  int gr = blockIdx.x, t = threadIdx.x;
  sg[t] = g[gr * 128 + t];
  __syncthreads();
  const float* W = (t < 64) ? Wm : Wl;
  const float* b = (t < 64) ? bm : bl;
  int c = t & 63;
  float acc = b[c];
  #pragma unroll 8
  for (int k = 0; k < 128; ++k) acc += sg[k] * W[k * 64 + c];
  out[(size_t)(t < 64 ? 0 : N_GRAPHS * 64) + (size_t)gr * 64 + c] = acc;
}

// ---------------- host ----------------
extern "C" void kernel_launch(void* const* d_in, const int* in_sizes, int n_in,
                              void* d_out, int out_size, void* d_ws, size_t ws_size,
                              hipStream_t stream) {
  const float* x      = (const float*)d_in[0];
  const int* e32      = (const int*)d_in[1];
  const long long* e64 = (const long long*)d_in[1];
  const int* batch    = (const int*)d_in[2];
  const float* W_in   = (const float*)d_in[3];
  const float* b_in   = (const float*)d_in[4];
  const float* W_msg  = (const float*)d_in[5];
  const float* b_msg  = (const float*)d_in[6];
  const float* W_upd  = (const float*)d_in[7];
  const float* b_upd  = (const float*)d_in[8];
  const float* W_mean = (const float*)d_in[9];
  const float* b_mean = (const float*)d_in[10];
  const float* W_lv   = (const float*)d_in[11];
  const float* b_lv   = (const float*)d_in[12];
  float* out = (float*)d_out;

  char* p = (char*)d_ws;
  auto alloc = [&](size_t bytes) {
    char* r = p;
    p += (bytes + 255) & ~(size_t)255;
    return r;
  };
  ushort* xb   = (ushort*)alloc((size_t)N_NODES * 128 * 2);
  ushort* bufA = (ushort*)alloc((size_t)N_NODES * 128 * 2);
  ushort* bufB = (ushort*)alloc((size_t)N_NODES * 128 * 2);
  ushort* bufC = (ushort*)alloc((size_t)N_NODES * 128 * 2);
  ushort* Wt   = (ushort*)alloc((size_t)7 * 16384 * 2);
  int* srcs    = (int*)alloc((size_t)N_EDGES * 4);
  int* deg     = (int*)alloc((size_t)(N_NODES + 4) * 4);
  int* rptr    = (int*)alloc((size_t)(N_NODES + 4) * 4);
  int* cursor  = (int*)alloc((size_t)N_NODES * 4);
  int* bsum    = (int*)alloc(64 * 4);
  int* flag    = (int*)alloc(64 * 4);
  float* g     = (float*)alloc((size_t)N_GRAPHS * 128 * 4);

  hipMemsetAsync(deg, 0, (size_t)N_NODES * 4, stream);
  hipMemsetAsync(cursor, 0, (size_t)N_NODES * 4, stream);
  hipMemsetAsync(g, 0, (size_t)N_GRAPHS * 128 * 4, stream);

  // CSR build
  k_detect64<<<1, 64, 0, stream>>>(e32, flag);
  k_degree<<<(N_EDGES + 255) / 256, 256, 0, stream>>>(e32, e64, flag, deg);
  k_scan_block<<<25, 1024, 0, stream>>>(deg, rptr, bsum);
  k_scan_sums<<<1, 64, 0, stream>>>(bsum);
  k_scan_add<<<(N_NODES + 1023) / 1024, 1024, 0, stream>>>(rptr, bsum);
  k_fill<<<(N_EDGES + 255) / 256, 256, 0, stream>>>(e32, e64, flag, rptr, cursor, srcs);

  // prep: bf16 conversions
  k_cvt_x<<<(N_NODES * 128) / (256 * 8), 256, 0, stream>>>(x, xb);
  k_prep_w<<<7, 256, 0, stream>>>(W_in, W_msg, W_upd, Wt);

  const int GB = (N_NODES + 63) / 64;

  // input layer: h = relu(x @ W_in + b_in)
  k_gemm_bf16<false><<<GB, 256, 0, stream>>>(xb, Wt, b_in, nullptr, bufA);

  ushort* h = bufA;
  ushort* tmp = bufB;
  for (int l = 0; l < N_LAYERS; ++l) {
    const ushort* Wm = Wt + (size_t)(1 + l) * 16384;
    const float* bm = b_msg + (size_t)l * 128;
    const ushort* Wu = Wt + (size_t)(4 + l) * 16384;
    const float* bu = b_upd + (size_t)l * 128;
    k_gemm_bf16<false><<<GB, 256, 0, stream>>>(h, Wm, bm, nullptr, tmp);
    k_aggregate<<<N_NODES / 4, 256, 0, stream>>>(rptr, srcs, tmp, bufC);
    k_gemm_bf16<true><<<GB, 256, 0, stream>>>(bufC, Wu, bu, h, tmp);
    ushort* sw = h; h = tmp; tmp = sw;
  }

  // graph pooling + heads
  k_pool<<<(N_NODES + 255) / 256, 128, 0, stream>>>(h, batch, g);
  k_head<<<N_GRAPHS, 128, 0, stream>>>(g, W_mean, b_mean, W_lv, b_lv, out);
}